// Round 1
// baseline (397.957 us; speedup 1.0000x reference)
//
#include <hip/hip_runtime.h>

// Cuboid (windowed) self-attention, B=2,T=8,H=W=64,C=256, HEADS=8, WS=8.
// Windows: Bw = 2*8*8 = 128, tokens/window N = 8*8*8 = 512, dh = 32.
// Pipeline: k_prep (weightsT->bf16, fold softmax scale*log2e into Q cols)
//           k_qkv  (window-partition + x@qkv_w, bf16 MFMA 16x16x32)
//           k_attn (per (window,head): S^T = K*Q^T swapped-MFMA, in-reg softmax, PV)
//           k_proj (O@proj_w + b, window reverse, fp32 out)

typedef __bf16 bf16x8 __attribute__((ext_vector_type(8)));
typedef float f32x4 __attribute__((ext_vector_type(4)));

#define NTOK 512
#define DH 32
#define CDIM 256
#define C3 768

__device__ __forceinline__ unsigned short f2b(float f) {
  unsigned u = __builtin_bit_cast(unsigned, f);
  unsigned r = u + 0x7fffu + ((u >> 16) & 1u);   // RNE, inputs finite
  return (unsigned short)(r >> 16);
}

// ---------------- kernel 0: weight prep ----------------
__global__ void k_prep(const float* __restrict__ qkv_w, const float* __restrict__ proj_w,
                       unsigned short* __restrict__ wqT, unsigned short* __restrict__ wpT) {
  // wqT[n][k] = qkv_w[k][n] * (n<256 ? scale*log2e : 1);  wpT[n][k] = proj_w[k][n]
  const float QS = 0.2550540254f;  // 32^-0.5 * log2(e)
  int idx = blockIdx.x * 256 + threadIdx.x;
  int stride = gridDim.x * 256;
  for (int i = idx; i < C3 * CDIM; i += stride) {
    int n = i >> 8, kk = i & 255;
    float f = qkv_w[kk * C3 + n];
    if (n < 256) f *= QS;
    wqT[i] = f2b(f);
  }
  for (int i = idx; i < CDIM * CDIM; i += stride) {
    int n = i >> 8, kk = i & 255;
    wpT[i] = f2b(proj_w[kk * CDIM + n]);
  }
}

// ---------------- kernel 1: QKV GEMM (window partition fused) ----------------
// grid 512 blocks, 256 thr. Block = 128-row M-tile (one quarter window).
// LDS: A full-K [128][264] bf16 (row pad 264 vs 256 -> conflict-free-ish) + B tile [128][40].
__global__ __launch_bounds__(256, 2) void k_qkv(
    const float* __restrict__ x, const unsigned short* __restrict__ wqT,
    unsigned short* __restrict__ qo, unsigned short* __restrict__ ko,
    unsigned short* __restrict__ vo) {
  extern __shared__ char smem[];
  unsigned short (*As)[264] = (unsigned short (*)[264])smem;
  unsigned short (*Bs)[40]  = (unsigned short (*)[40])(smem + 128 * 264 * 2);
  int tid = threadIdx.x;
  int mtile = blockIdx.x;
  int bw = mtile >> 2;             // window id (512 rows / 128 = 4 tiles per window)
  int n0 = (mtile & 3) << 7;       // token offset inside window
  int bb = bw >> 6, hi = (bw >> 3) & 7, wi = bw & 7;

  {  // stage A: rows gathered by window partition, fp32 -> bf16
    int row = tid >> 1;
    int n = n0 + row;
    int tt = n >> 6, ii = (n >> 3) & 7, jj = n & 7;
    const float* src = x + ((((long)(bb * 8 + tt)) * 64 + (hi * 8 + ii)) * 64 + (wi * 8 + jj)) * 256;
    int fb = (tid & 1) * 4;
#pragma unroll
    for (int u = 0; u < 32; ++u) {
      int f = fb + u * 8;
      float4 d = *(const float4*)(src + f);
      ushort4 h;
      h.x = f2b(d.x); h.y = f2b(d.y); h.z = f2b(d.z); h.w = f2b(d.w);
      *(ushort4*)&As[row][f] = h;
    }
  }
  __syncthreads();

  int wid = tid >> 6, lane = tid & 63;
  int lg = lane >> 4, lr = lane & 15;
  int wr = wid >> 1, wc = wid & 1;

  for (int nt = 0; nt < 6; ++nt) {
    f32x4 acc[4][4];
#pragma unroll
    for (int a = 0; a < 4; ++a)
#pragma unroll
      for (int b2 = 0; b2 < 4; ++b2) acc[a][b2] = (f32x4){0.f, 0.f, 0.f, 0.f};

    for (int kk = 0; kk < 256; kk += 32) {
      __syncthreads();
      {  // stage B tile [128 cols of qkv][32 k] from wqT (bf16 copy)
        int brow = tid >> 1, bh2 = tid & 1;
        const uint4* bs = (const uint4*)(wqT + ((long)(nt * 128 + brow)) * 256 + kk + bh2 * 16);
        uint4 b0 = bs[0], b1 = bs[1];
        *(uint4*)&Bs[brow][bh2 * 16] = b0;
        *(uint4*)&Bs[brow][bh2 * 16 + 8] = b1;
      }
      __syncthreads();
      bf16x8 af[4], bfr[4];
#pragma unroll
      for (int mi = 0; mi < 4; ++mi)
        af[mi] = *(const bf16x8*)&As[wr * 64 + mi * 16 + lr][kk + lg * 8];
#pragma unroll
      for (int ni = 0; ni < 4; ++ni)
        bfr[ni] = *(const bf16x8*)&Bs[wc * 64 + ni * 16 + lr][lg * 8];
#pragma unroll
      for (int mi = 0; mi < 4; ++mi)
#pragma unroll
        for (int ni = 0; ni < 4; ++ni)
          acc[mi][ni] = __builtin_amdgcn_mfma_f32_16x16x32_bf16(af[mi], bfr[ni], acc[mi][ni], 0, 0, 0);
    }
    // epilogue: split q/k/v by output column; layout [bw][head][n][d] bf16
#pragma unroll
    for (int ni = 0; ni < 4; ++ni) {
      int c = nt * 128 + wc * 64 + ni * 16 + lr;
      int which = c >> 8, head = (c >> 5) & 7, d = c & 31;
      unsigned short* dst = (which == 0) ? qo : ((which == 1) ? ko : vo);
      long base = ((long)(bw * 8 + head)) * NTOK * DH + d;
#pragma unroll
      for (int mi = 0; mi < 4; ++mi) {
        int nloc = n0 + wr * 64 + mi * 16 + lg * 4;
#pragma unroll
        for (int r = 0; r < 4; ++r)
          dst[base + (long)(nloc + r) * DH] = f2b(acc[mi][ni][r]);
      }
    }
  }
}

// ---------------- kernel 2: attention per (window, head) ----------------
// grid 1024 blocks, 256 thr (4 waves). LDS: K [512][40] bf16 @0 (40960B),
// V^T [32][520] bf16 @40960 (33280B), P per-wave [16][40] @74240 (4*1280B). total 79360B.
// Swapped QK^T: S^T tile = mfma(A=K_tile, B=Q^T) -> lane owns q-row (lane&15), m = 16t+4g+r.
__global__ __launch_bounds__(256, 2) void k_attn(
    const unsigned short* __restrict__ qg0, const unsigned short* __restrict__ kg0,
    const unsigned short* __restrict__ vg0, unsigned short* __restrict__ og) {
  extern __shared__ char smem[];
  int bh = blockIdx.x;
  int tid = threadIdx.x;
  const unsigned short* qg = qg0 + (long)bh * NTOK * DH;
  const unsigned short* kg = kg0 + (long)bh * NTOK * DH;
  const unsigned short* vg = vg0 + (long)bh * NTOK * DH;

  // stage K: [n][d] rows of 32 bf16, padded to 40
#pragma unroll
  for (int i2 = 0; i2 < 8; ++i2) {
    int ci = tid + i2 * 256;  // 16B chunk id: n = ci>>2, quarter h = ci&3
    uint4 dd = *(const uint4*)(kg + ci * 8);
    int n = ci >> 2, h = ci & 3;
    *(uint4*)(smem + n * 80 + h * 16) = dd;
  }
  // stage V^T: thread t owns rows n=2t,2t+1; column writes are conflict-free
  {
    const uint4* vs = (const uint4*)(vg + tid * 64);
    unsigned r0[16], r1[16];
    *(uint4*)&r0[0] = vs[0]; *(uint4*)&r0[4] = vs[1]; *(uint4*)&r0[8] = vs[2]; *(uint4*)&r0[12] = vs[3];
    *(uint4*)&r1[0] = vs[4]; *(uint4*)&r1[4] = vs[5]; *(uint4*)&r1[8] = vs[6]; *(uint4*)&r1[12] = vs[7];
#pragma unroll
    for (int d = 0; d < 32; ++d) {
      unsigned lo  = (r0[d >> 1] >> ((d & 1) * 16)) & 0xffffu;
      unsigned hi2 = (r1[d >> 1] >> ((d & 1) * 16)) & 0xffffu;
      *(unsigned*)(smem + 40960 + d * 1040 + tid * 4) = lo | (hi2 << 16);
    }
  }
  __syncthreads();

  int wid = tid >> 6, lane = tid & 63;
  int lg = lane >> 4, lr = lane & 15;
  char* Pb = smem + 74240 + wid * 1280;
  int bw = bh >> 3, head = bh & 7;
  unsigned short* ob = og + (long)bw * NTOK * CDIM + head * DH;  // O layout [bw][n][c]
  const f32x4 zf = {0.f, 0.f, 0.f, 0.f};

  for (int pass = 0; pass < 8; ++pass) {
    int qrow = pass * 64 + wid * 16;
    bf16x8 qf = *(const bf16x8*)(qg + (qrow + lr) * DH + lg * 8);
    f32x4 s[32];
#pragma unroll
    for (int t = 0; t < 32; ++t) {
      bf16x8 kf = *(const bf16x8*)(smem + (t * 16 + lr) * 80 + lg * 16);
      s[t] = __builtin_amdgcn_mfma_f32_16x16x32_bf16(kf, qf, zf, 0, 0, 0);
    }
    // softmax over m (Q pre-scaled by scale*log2e -> exp2)
    float m = -3e38f;
#pragma unroll
    for (int t = 0; t < 32; ++t)
#pragma unroll
      for (int r = 0; r < 4; ++r) m = fmaxf(m, s[t][r]);
    m = fmaxf(m, __shfl_xor(m, 16, 64));
    m = fmaxf(m, __shfl_xor(m, 32, 64));
    float sum = 0.f;
#pragma unroll
    for (int t = 0; t < 32; ++t)
#pragma unroll
      for (int r = 0; r < 4; ++r) {
        float p = exp2f(s[t][r] - m);
        s[t][r] = p;
        sum += p;
      }
    sum += __shfl_xor(sum, 16, 64);
    sum += __shfl_xor(sum, 32, 64);

    f32x4 o0 = zf, o1 = zf;
#pragma unroll
    for (int mc = 0; mc < 16; ++mc) {
      // bounce this 16x32 P-chunk through per-wave LDS (layout P[n][m], n=lr)
#pragma unroll
      for (int u = 0; u < 2; ++u) {
        int t = mc * 2 + u;
        ushort4 pk;
        pk.x = f2b(s[t][0]); pk.y = f2b(s[t][1]); pk.z = f2b(s[t][2]); pk.w = f2b(s[t][3]);
        *(ushort4*)(Pb + lr * 80 + u * 32 + lg * 8) = pk;
      }
      bf16x8 pf = *(const bf16x8*)(Pb + lr * 80 + lg * 16);
      bf16x8 v0 = *(const bf16x8*)(smem + 40960 + (lr) * 1040 + mc * 64 + lg * 16);
      bf16x8 v1 = *(const bf16x8*)(smem + 40960 + (16 + lr) * 1040 + mc * 64 + lg * 16);
      o0 = __builtin_amdgcn_mfma_f32_16x16x32_bf16(pf, v0, o0, 0, 0, 0);
      o1 = __builtin_amdgcn_mfma_f32_16x16x32_bf16(pf, v1, o1, 0, 0, 0);
    }
    // divide by softmax denom (sum lives at lane == row index) and store
    float rcp = 1.0f / sum;
#pragma unroll
    for (int r = 0; r < 4; ++r) {
      float rr = __shfl(rcp, lg * 4 + r, 64);
      int n = qrow + lg * 4 + r;
      ob[(long)n * CDIM + lr]      = f2b(o0[r] * rr);
      ob[(long)n * CDIM + 16 + lr] = f2b(o1[r] * rr);
    }
  }
}

// ---------------- kernel 3: proj GEMM + bias + window reverse ----------------
__global__ __launch_bounds__(256, 2) void k_proj(
    const unsigned short* __restrict__ og, const unsigned short* __restrict__ wpT,
    const float* __restrict__ pb, float* __restrict__ out) {
  extern __shared__ char smem[];
  unsigned short (*As)[264] = (unsigned short (*)[264])smem;
  unsigned short (*Bs)[40]  = (unsigned short (*)[40])(smem + 128 * 264 * 2);
  int tid = threadIdx.x;
  int mtile = blockIdx.x;
  int bw = mtile >> 2;
  int n0 = (mtile & 3) << 7;
  int bb = bw >> 6, hi = (bw >> 3) & 7, wi = bw & 7;

  {  // stage A (already bf16, contiguous rows)
    int row = tid >> 1, hf = tid & 1;
    const uint4* asrc = (const uint4*)(og + ((long)bw * NTOK + n0 + row) * CDIM + hf * 128);
#pragma unroll
    for (int u = 0; u < 16; ++u) {
      uint4 dd = asrc[u];
      *(uint4*)&As[row][hf * 128 + u * 8] = dd;
    }
  }
  __syncthreads();

  int wid = tid >> 6, lane = tid & 63;
  int lg = lane >> 4, lr = lane & 15;
  int wr = wid >> 1, wc = wid & 1;

  for (int nt = 0; nt < 2; ++nt) {
    f32x4 acc[4][4];
#pragma unroll
    for (int a = 0; a < 4; ++a)
#pragma unroll
      for (int b2 = 0; b2 < 4; ++b2) acc[a][b2] = (f32x4){0.f, 0.f, 0.f, 0.f};

    for (int kk = 0; kk < 256; kk += 32) {
      __syncthreads();
      {
        int brow = tid >> 1, bh2 = tid & 1;
        const uint4* bs = (const uint4*)(wpT + ((long)(nt * 128 + brow)) * 256 + kk + bh2 * 16);
        uint4 b0 = bs[0], b1 = bs[1];
        *(uint4*)&Bs[brow][bh2 * 16] = b0;
        *(uint4*)&Bs[brow][bh2 * 16 + 8] = b1;
      }
      __syncthreads();
      bf16x8 af[4], bfr[4];
#pragma unroll
      for (int mi = 0; mi < 4; ++mi)
        af[mi] = *(const bf16x8*)&As[wr * 64 + mi * 16 + lr][kk + lg * 8];
#pragma unroll
      for (int ni = 0; ni < 4; ++ni)
        bfr[ni] = *(const bf16x8*)&Bs[wc * 64 + ni * 16 + lr][lg * 8];
#pragma unroll
      for (int mi = 0; mi < 4; ++mi)
#pragma unroll
        for (int ni = 0; ni < 4; ++ni)
          acc[mi][ni] = __builtin_amdgcn_mfma_f32_16x16x32_bf16(af[mi], bfr[ni], acc[mi][ni], 0, 0, 0);
    }
    // epilogue: bias + window reverse, coalesced fp32 (16 lanes -> 64B)
#pragma unroll
    for (int ni = 0; ni < 4; ++ni) {
      int c = nt * 128 + wc * 64 + ni * 16 + lr;
      float bias = pb[c];
#pragma unroll
      for (int mi = 0; mi < 4; ++mi) {
        int nbase = n0 + wr * 64 + mi * 16 + lg * 4;
#pragma unroll
        for (int r = 0; r < 4; ++r) {
          int n = nbase + r;
          int tt = n >> 6, ii = (n >> 3) & 7, jj = n & 7;
          long off = ((((long)(bb * 8 + tt)) * 64 + (hi * 8 + ii)) * 64 + (wi * 8 + jj)) * 256 + c;
          out[off] = acc[mi][ni][r] + bias;
        }
      }
    }
  }
}

extern "C" void kernel_launch(void* const* d_in, const int* in_sizes, int n_in,
                              void* d_out, int out_size, void* d_ws, size_t ws_size,
                              hipStream_t stream) {
  const float* x      = (const float*)d_in[0];
  const float* qkv_w  = (const float*)d_in[1];
  const float* proj_w = (const float*)d_in[2];
  const float* proj_b = (const float*)d_in[3];
  float* out = (float*)d_out;
  char* ws = (char*)d_ws;

  // workspace layout (bytes): wqT 393216 | wpT 131072 | Q 32MiB | K 32MiB | V 32MiB | O 32MiB
  unsigned short* wqT = (unsigned short*)(ws);
  unsigned short* wpT = (unsigned short*)(ws + 393216);
  unsigned short* Q   = (unsigned short*)(ws + 524288);
  unsigned short* K   = (unsigned short*)(ws + 524288 + 1L * 33554432);
  unsigned short* V   = (unsigned short*)(ws + 524288 + 2L * 33554432);
  unsigned short* O   = (unsigned short*)(ws + 524288 + 3L * 33554432);

  (void)hipFuncSetAttribute((const void*)k_qkv,  hipFuncAttributeMaxDynamicSharedMemorySize, 77824);
  (void)hipFuncSetAttribute((const void*)k_attn, hipFuncAttributeMaxDynamicSharedMemorySize, 79360);
  (void)hipFuncSetAttribute((const void*)k_proj, hipFuncAttributeMaxDynamicSharedMemorySize, 77824);

  k_prep<<<256, 256, 0, stream>>>(qkv_w, proj_w, wqT, wpT);
  k_qkv<<<512, 256, 77824, stream>>>(x, wqT, Q, K, V);
  k_attn<<<1024, 256, 79360, stream>>>(Q, K, V, O);
  k_proj<<<512, 256, 77824, stream>>>(O, wpT, proj_b, out);
}

// Round 3
// 181.793 us; speedup vs baseline: 2.1891x; 2.1891x over previous
//
#include <hip/hip_runtime.h>

// Cuboid (windowed) self-attention, B=2,T=8,H=W=64,C=256, HEADS=8, WS=8.
// Windows: Bw = 2*8*8 = 128, tokens/window N = 8*8*8 = 512, dh = 32.
// Pipeline: k_prep (weightsT->bf16, fold softmax scale*log2e into Q cols)
//           k_qkv  (window-partition + x@qkv_w, bf16 MFMA 16x16x32)
//           k_attn (per (window,head): swapped-MFMA QK^T, online softmax in 4 chunks
//                   of 128 cols -> no VGPR spill; O stored contiguous via LDS transpose)
//           k_proj (O@proj_w + b, window reverse, fp32 out)

typedef __bf16 bf16x8 __attribute__((ext_vector_type(8)));
typedef float f32x4 __attribute__((ext_vector_type(4)));

#define NTOK 512
#define DH 32
#define CDIM 256
#define C3 768

__device__ __forceinline__ unsigned short f2b(float f) {
  unsigned u = __builtin_bit_cast(unsigned, f);
  unsigned r = u + 0x7fffu + ((u >> 16) & 1u);   // RNE, inputs finite
  return (unsigned short)(r >> 16);
}

// ---------------- kernel 0: weight prep ----------------
__global__ void k_prep(const float* __restrict__ qkv_w, const float* __restrict__ proj_w,
                       unsigned short* __restrict__ wqT, unsigned short* __restrict__ wpT) {
  // wqT[n][k] = qkv_w[k][n] * (n<256 ? scale*log2e : 1);  wpT[n][k] = proj_w[k][n]
  const float QS = 0.2550540254f;  // 32^-0.5 * log2(e)
  int idx = blockIdx.x * 256 + threadIdx.x;
  int stride = gridDim.x * 256;
  for (int i = idx; i < C3 * CDIM; i += stride) {
    int n = i >> 8, kk = i & 255;
    float f = qkv_w[kk * C3 + n];
    if (n < 256) f *= QS;
    wqT[i] = f2b(f);
  }
  for (int i = idx; i < CDIM * CDIM; i += stride) {
    int n = i >> 8, kk = i & 255;
    wpT[i] = f2b(proj_w[kk * CDIM + n]);
  }
}

// ---------------- kernel 1: QKV GEMM (window partition fused) ----------------
// grid 512 blocks, 256 thr. Block = 128-row M-tile (one quarter window).
// LDS: A full-K [128][264] bf16 + B tile [128][40].
__global__ __launch_bounds__(256, 2) void k_qkv(
    const float* __restrict__ x, const unsigned short* __restrict__ wqT,
    unsigned short* __restrict__ qo, unsigned short* __restrict__ ko,
    unsigned short* __restrict__ vo) {
  extern __shared__ char smem[];
  unsigned short (*As)[264] = (unsigned short (*)[264])smem;
  unsigned short (*Bs)[40]  = (unsigned short (*)[40])(smem + 128 * 264 * 2);
  int tid = threadIdx.x;
  int mtile = blockIdx.x;
  int bw = mtile >> 2;             // window id (512 rows / 128 = 4 tiles per window)
  int n0 = (mtile & 3) << 7;       // token offset inside window
  int bb = bw >> 6, hi = (bw >> 3) & 7, wi = bw & 7;

  {  // stage A: rows gathered by window partition, fp32 -> bf16
    int row = tid >> 1;
    int n = n0 + row;
    int tt = n >> 6, ii = (n >> 3) & 7, jj = n & 7;
    const float* src = x + ((((long)(bb * 8 + tt)) * 64 + (hi * 8 + ii)) * 64 + (wi * 8 + jj)) * 256;
    int fb = (tid & 1) * 4;
#pragma unroll
    for (int u = 0; u < 32; ++u) {
      int f = fb + u * 8;
      float4 d = *(const float4*)(src + f);
      ushort4 h;
      h.x = f2b(d.x); h.y = f2b(d.y); h.z = f2b(d.z); h.w = f2b(d.w);
      *(ushort4*)&As[row][f] = h;
    }
  }
  __syncthreads();

  int wid = tid >> 6, lane = tid & 63;
  int lg = lane >> 4, lr = lane & 15;
  int wr = wid >> 1, wc = wid & 1;

  for (int nt = 0; nt < 6; ++nt) {
    f32x4 acc[4][4];
#pragma unroll
    for (int a = 0; a < 4; ++a)
#pragma unroll
      for (int b2 = 0; b2 < 4; ++b2) acc[a][b2] = (f32x4){0.f, 0.f, 0.f, 0.f};

    for (int kk = 0; kk < 256; kk += 32) {
      __syncthreads();
      {  // stage B tile [128 cols of qkv][32 k] from wqT (bf16 copy)
        int brow = tid >> 1, bh2 = tid & 1;
        const uint4* bs = (const uint4*)(wqT + ((long)(nt * 128 + brow)) * 256 + kk + bh2 * 16);
        uint4 b0 = bs[0], b1 = bs[1];
        *(uint4*)&Bs[brow][bh2 * 16] = b0;
        *(uint4*)&Bs[brow][bh2 * 16 + 8] = b1;
      }
      __syncthreads();
      bf16x8 af[4], bfr[4];
#pragma unroll
      for (int mi = 0; mi < 4; ++mi)
        af[mi] = *(const bf16x8*)&As[wr * 64 + mi * 16 + lr][kk + lg * 8];
#pragma unroll
      for (int ni = 0; ni < 4; ++ni)
        bfr[ni] = *(const bf16x8*)&Bs[wc * 64 + ni * 16 + lr][lg * 8];
#pragma unroll
      for (int mi = 0; mi < 4; ++mi)
#pragma unroll
        for (int ni = 0; ni < 4; ++ni)
          acc[mi][ni] = __builtin_amdgcn_mfma_f32_16x16x32_bf16(af[mi], bfr[ni], acc[mi][ni], 0, 0, 0);
    }
    // epilogue: split q/k/v by output column; layout [bw][head][n][d] bf16
#pragma unroll
    for (int ni = 0; ni < 4; ++ni) {
      int c = nt * 128 + wc * 64 + ni * 16 + lr;
      int which = c >> 8, head = (c >> 5) & 7, d = c & 31;
      unsigned short* dst = (which == 0) ? qo : ((which == 1) ? ko : vo);
      long base = ((long)(bw * 8 + head)) * NTOK * DH + d;
#pragma unroll
      for (int mi = 0; mi < 4; ++mi) {
        int nloc = n0 + wr * 64 + mi * 16 + lg * 4;
#pragma unroll
        for (int r = 0; r < 4; ++r)
          dst[base + (long)(nloc + r) * DH] = f2b(acc[mi][ni][r]);
      }
    }
  }
}

// ---------------- kernel 2: attention per (window, head) ----------------
// grid 1024 blocks, 256 thr (4 waves). LDS: K [512][40] bf16 @0 (40960B),
// V^T [32][520] bf16 @40960 (33280B), P per-wave [16][40] @74240 (4*1280B). total 79360B.
// Swapped QK^T: S^T tile = mfma(A=K_tile, B=Q^T) -> lane (lg,lr) holds
// S[m=16t+4lg+r][q=qrow+lr]. Online softmax over 4 chunks of 128 m-columns
// keeps live S at 8 f32x4 (32 VGPR) -> no spill.
// O layout: [bw*8+head][n][32] (block-contiguous); stored via LDS transpose, 16B stores.
__global__ __launch_bounds__(256, 2) void k_attn(
    const unsigned short* __restrict__ qg0, const unsigned short* __restrict__ kg0,
    const unsigned short* __restrict__ vg0, unsigned short* __restrict__ og) {
  extern __shared__ char smem[];
  int bh = blockIdx.x;
  int tid = threadIdx.x;
  const unsigned short* qg = qg0 + (long)bh * NTOK * DH;
  const unsigned short* kg = kg0 + (long)bh * NTOK * DH;
  const unsigned short* vg = vg0 + (long)bh * NTOK * DH;

  // stage K: [n][d] rows of 32 bf16, padded to 40
#pragma unroll
  for (int i2 = 0; i2 < 8; ++i2) {
    int ci = tid + i2 * 256;  // 16B chunk id: n = ci>>2, quarter h = ci&3
    uint4 dd = *(const uint4*)(kg + ci * 8);
    int n = ci >> 2, h = ci & 3;
    *(uint4*)(smem + n * 80 + h * 16) = dd;
  }
  // stage V^T: thread t owns rows n=2t,2t+1; column writes are conflict-free
  {
    const uint4* vs = (const uint4*)(vg + tid * 64);
    unsigned r0[16], r1[16];
    *(uint4*)&r0[0] = vs[0]; *(uint4*)&r0[4] = vs[1]; *(uint4*)&r0[8] = vs[2]; *(uint4*)&r0[12] = vs[3];
    *(uint4*)&r1[0] = vs[4]; *(uint4*)&r1[4] = vs[5]; *(uint4*)&r1[8] = vs[6]; *(uint4*)&r1[12] = vs[7];
#pragma unroll
    for (int d = 0; d < 32; ++d) {
      unsigned lo  = (r0[d >> 1] >> ((d & 1) * 16)) & 0xffffu;
      unsigned hi2 = (r1[d >> 1] >> ((d & 1) * 16)) & 0xffffu;
      *(unsigned*)(smem + 40960 + d * 1040 + tid * 4) = lo | (hi2 << 16);
    }
  }
  __syncthreads();

  int wid = tid >> 6, lane = tid & 63;
  int lg = lane >> 4, lr = lane & 15;
  char* Pb = smem + 74240 + wid * 1280;
  unsigned short* ob = og + (long)bh * NTOK * DH;  // block-contiguous O
  const f32x4 zf = {0.f, 0.f, 0.f, 0.f};

  for (int pass = 0; pass < 8; ++pass) {
    int qrow = pass * 64 + wid * 16;
    bf16x8 qf = *(const bf16x8*)(qg + (qrow + lr) * DH + lg * 8);
    f32x4 o0 = zf, o1 = zf;
    float m_run = -1e30f, sum = 0.f;

    for (int ch = 0; ch < 4; ++ch) {
      f32x4 s[8];
#pragma unroll
      for (int t = 0; t < 8; ++t) {
        bf16x8 kf = *(const bf16x8*)(smem + ((ch * 8 + t) * 16 + lr) * 80 + lg * 16);
        s[t] = __builtin_amdgcn_mfma_f32_16x16x32_bf16(kf, qf, zf, 0, 0, 0);
      }
      // chunk max (per q-row = lr; reduce in-lane then across lg via xor 16/32)
      float mc = -1e30f;
#pragma unroll
      for (int t = 0; t < 8; ++t)
#pragma unroll
        for (int r = 0; r < 4; ++r) mc = fmaxf(mc, s[t][r]);
      mc = fmaxf(mc, __shfl_xor(mc, 16, 64));
      mc = fmaxf(mc, __shfl_xor(mc, 32, 64));
      float nm = fmaxf(m_run, mc);
      float sc = __builtin_amdgcn_exp2f(m_run - nm);
      m_run = nm;
      float psum = 0.f;
#pragma unroll
      for (int t = 0; t < 8; ++t)
#pragma unroll
        for (int r = 0; r < 4; ++r) {
          float p = __builtin_amdgcn_exp2f(s[t][r] - nm);
          s[t][r] = p;
          psum += p;
        }
      psum += __shfl_xor(psum, 16, 64);
      psum += __shfl_xor(psum, 32, 64);
      sum = sum * sc + psum;
      // rescale O accumulators (row n=4lg+r lives at softmax lane id 4lg+r)
#pragma unroll
      for (int r = 0; r < 4; ++r) {
        float so = __shfl(sc, lg * 4 + r, 64);
        o0[r] *= so;
        o1[r] *= so;
      }
      // PV over this chunk: 4 groups of 32 m-columns, P bounced via per-wave LDS
#pragma unroll
      for (int mcl = 0; mcl < 4; ++mcl) {
#pragma unroll
        for (int u = 0; u < 2; ++u) {
          int t = mcl * 2 + u;
          ushort4 pk;
          pk.x = f2b(s[t][0]); pk.y = f2b(s[t][1]); pk.z = f2b(s[t][2]); pk.w = f2b(s[t][3]);
          *(ushort4*)(Pb + lr * 80 + u * 32 + lg * 8) = pk;
        }
        bf16x8 pf = *(const bf16x8*)(Pb + lr * 80 + lg * 16);
        int mg = ch * 4 + mcl;
        bf16x8 v0 = *(const bf16x8*)(smem + 40960 + (lr) * 1040 + mg * 64 + lg * 16);
        bf16x8 v1 = *(const bf16x8*)(smem + 40960 + (16 + lr) * 1040 + mg * 64 + lg * 16);
        o0 = __builtin_amdgcn_mfma_f32_16x16x32_bf16(pf, v0, o0, 0, 0, 0);
        o1 = __builtin_amdgcn_mfma_f32_16x16x32_bf16(pf, v1, o1, 0, 0, 0);
      }
    }

    // normalize + transpose through Pb -> contiguous 16B stores
    float rcp = 1.0f / sum;
#pragma unroll
    for (int r = 0; r < 4; ++r) {
      float rr = __shfl(rcp, lg * 4 + r, 64);
      int rowb = (lg * 4 + r) * 80;
      *(unsigned short*)(Pb + rowb + lr * 2)      = f2b(o0[r] * rr);
      *(unsigned short*)(Pb + rowb + 32 + lr * 2) = f2b(o1[r] * rr);
    }
    {
      int row = lane >> 2, qq = lane & 3;
      uint4 dd = *(const uint4*)(Pb + row * 80 + qq * 16);
      *(uint4*)(ob + ((long)(qrow + row)) * DH + qq * 8) = dd;
    }
  }
}

// ---------------- kernel 3: proj GEMM + bias + window reverse ----------------
__global__ __launch_bounds__(256, 2) void k_proj(
    const unsigned short* __restrict__ og, const unsigned short* __restrict__ wpT,
    const float* __restrict__ pb, float* __restrict__ out) {
  extern __shared__ char smem[];
  unsigned short (*As)[264] = (unsigned short (*)[264])smem;
  unsigned short (*Bs)[40]  = (unsigned short (*)[40])(smem + 128 * 264 * 2);
  int tid = threadIdx.x;
  int mtile = blockIdx.x;
  int bw = mtile >> 2;
  int n0 = (mtile & 3) << 7;
  int bb = bw >> 6, hi = (bw >> 3) & 7, wi = bw & 7;

  {  // stage A from O layout [bw*8+head][n][32]: 64B (4 x uint4) per head per row
    int row = tid >> 1, hf = tid & 1;
#pragma unroll
    for (int h4 = 0; h4 < 4; ++h4) {
      int h = hf * 4 + h4;
      const uint4* asrc = (const uint4*)(og + (((long)(bw * 8 + h)) * NTOK + n0 + row) * DH);
      uint4 d0 = asrc[0], d1 = asrc[1], d2 = asrc[2], d3 = asrc[3];
      *(uint4*)&As[row][h * 32]      = d0;
      *(uint4*)&As[row][h * 32 + 8]  = d1;
      *(uint4*)&As[row][h * 32 + 16] = d2;
      *(uint4*)&As[row][h * 32 + 24] = d3;
    }
  }
  __syncthreads();

  int wid = tid >> 6, lane = tid & 63;
  int lg = lane >> 4, lr = lane & 15;
  int wr = wid >> 1, wc = wid & 1;

  for (int nt = 0; nt < 2; ++nt) {
    f32x4 acc[4][4];
#pragma unroll
    for (int a = 0; a < 4; ++a)
#pragma unroll
      for (int b2 = 0; b2 < 4; ++b2) acc[a][b2] = (f32x4){0.f, 0.f, 0.f, 0.f};

    for (int kk = 0; kk < 256; kk += 32) {
      __syncthreads();
      {
        int brow = tid >> 1, bh2 = tid & 1;
        const uint4* bs = (const uint4*)(wpT + ((long)(nt * 128 + brow)) * 256 + kk + bh2 * 16);
        uint4 b0 = bs[0], b1 = bs[1];
        *(uint4*)&Bs[brow][bh2 * 16] = b0;
        *(uint4*)&Bs[brow][bh2 * 16 + 8] = b1;
      }
      __syncthreads();
      bf16x8 af[4], bfr[4];
#pragma unroll
      for (int mi = 0; mi < 4; ++mi)
        af[mi] = *(const bf16x8*)&As[wr * 64 + mi * 16 + lr][kk + lg * 8];
#pragma unroll
      for (int ni = 0; ni < 4; ++ni)
        bfr[ni] = *(const bf16x8*)&Bs[wc * 64 + ni * 16 + lr][lg * 8];
#pragma unroll
      for (int mi = 0; mi < 4; ++mi)
#pragma unroll
        for (int ni = 0; ni < 4; ++ni)
          acc[mi][ni] = __builtin_amdgcn_mfma_f32_16x16x32_bf16(af[mi], bfr[ni], acc[mi][ni], 0, 0, 0);
    }
    // epilogue: bias + window reverse, coalesced fp32 (16 lanes -> 64B)
#pragma unroll
    for (int ni = 0; ni < 4; ++ni) {
      int c = nt * 128 + wc * 64 + ni * 16 + lr;
      float bias = pb[c];
#pragma unroll
      for (int mi = 0; mi < 4; ++mi) {
        int nbase = n0 + wr * 64 + mi * 16 + lg * 4;
#pragma unroll
        for (int r = 0; r < 4; ++r) {
          int n = nbase + r;
          int tt = n >> 6, ii = (n >> 3) & 7, jj = n & 7;
          long off = ((((long)(bb * 8 + tt)) * 64 + (hi * 8 + ii)) * 64 + (wi * 8 + jj)) * 256 + c;
          out[off] = acc[mi][ni][r] + bias;
        }
      }
    }
  }
}

extern "C" void kernel_launch(void* const* d_in, const int* in_sizes, int n_in,
                              void* d_out, int out_size, void* d_ws, size_t ws_size,
                              hipStream_t stream) {
  const float* x      = (const float*)d_in[0];
  const float* qkv_w  = (const float*)d_in[1];
  const float* proj_w = (const float*)d_in[2];
  const float* proj_b = (const float*)d_in[3];
  float* out = (float*)d_out;
  char* ws = (char*)d_ws;

  // workspace layout (bytes): wqT 393216 | wpT 131072 | Q 32MiB | K 32MiB | V 32MiB | O 32MiB
  unsigned short* wqT = (unsigned short*)(ws);
  unsigned short* wpT = (unsigned short*)(ws + 393216);
  unsigned short* Q   = (unsigned short*)(ws + 524288);
  unsigned short* K   = (unsigned short*)(ws + 524288 + 1L * 33554432);
  unsigned short* V   = (unsigned short*)(ws + 524288 + 2L * 33554432);
  unsigned short* O   = (unsigned short*)(ws + 524288 + 3L * 33554432);

  (void)hipFuncSetAttribute((const void*)k_qkv,  hipFuncAttributeMaxDynamicSharedMemorySize, 77824);
  (void)hipFuncSetAttribute((const void*)k_attn, hipFuncAttributeMaxDynamicSharedMemorySize, 79360);
  (void)hipFuncSetAttribute((const void*)k_proj, hipFuncAttributeMaxDynamicSharedMemorySize, 77824);

  k_prep<<<256, 256, 0, stream>>>(qkv_w, proj_w, wqT, wpT);
  k_qkv<<<512, 256, 77824, stream>>>(x, wqT, Q, K, V);
  k_attn<<<1024, 256, 79360, stream>>>(Q, K, V, O);
  k_proj<<<512, 256, 77824, stream>>>(O, wpT, proj_b, out);
}

// Round 6
// 156.001 us; speedup vs baseline: 2.5510x; 1.1653x over previous
//
#include <hip/hip_runtime.h>

// Cuboid (windowed) self-attention, B=2,T=8,H=W=64,C=256, HEADS=8, WS=8.
// Windows: Bw = 2*8*8 = 128, tokens/window N = 8*8*8 = 512, dh = 32.
// Pipeline: k_prep (weightsT->bf16, fold softmax scale*log2e into Q cols)
//           k_qkv  (window-partition + x@qkv_w, bf16 MFMA 16x16x32)
//           k_attn (per (window,head): swapped-MFMA QK^T, online softmax; round-3
//                   verified padded LDS layouts; 2 q-frags/wave/pass -> halved LDS reads)
//           k_proj (O@proj_w + b, window reverse, fp32 out)

typedef __bf16 bf16x8 __attribute__((ext_vector_type(8)));
typedef float f32x4 __attribute__((ext_vector_type(4)));

#define NTOK 512
#define DH 32
#define CDIM 256
#define C3 768

__device__ __forceinline__ unsigned short f2b(float f) {
  unsigned u = __builtin_bit_cast(unsigned, f);
  unsigned r = u + 0x7fffu + ((u >> 16) & 1u);   // RNE, inputs finite
  return (unsigned short)(r >> 16);
}

// ---------------- kernel 0: weight prep ----------------
__global__ void k_prep(const float* __restrict__ qkv_w, const float* __restrict__ proj_w,
                       unsigned short* __restrict__ wqT, unsigned short* __restrict__ wpT) {
  const float QS = 0.2550540254f;  // 32^-0.5 * log2(e)
  int idx = blockIdx.x * 256 + threadIdx.x;
  int stride = gridDim.x * 256;
  for (int i = idx; i < C3 * CDIM; i += stride) {
    int n = i >> 8, kk = i & 255;
    float f = qkv_w[kk * C3 + n];
    if (n < 256) f *= QS;
    wqT[i] = f2b(f);
  }
  for (int i = idx; i < CDIM * CDIM; i += stride) {
    int n = i >> 8, kk = i & 255;
    wpT[i] = f2b(proj_w[kk * CDIM + n]);
  }
}

// ---------------- kernel 1: QKV GEMM (window partition fused) ----------------
// grid 512 blocks, 256 thr. LDS: A full-K [128][264] bf16 + B tile [128][40].
__global__ __launch_bounds__(256, 2) void k_qkv(
    const float* __restrict__ x, const unsigned short* __restrict__ wqT,
    unsigned short* __restrict__ qo, unsigned short* __restrict__ ko,
    unsigned short* __restrict__ vo) {
  extern __shared__ char smem[];
  unsigned short (*As)[264] = (unsigned short (*)[264])smem;
  unsigned short (*Bs)[40]  = (unsigned short (*)[40])(smem + 128 * 264 * 2);
  int tid = threadIdx.x;
  int mtile = blockIdx.x;
  int bw = mtile >> 2;
  int n0 = (mtile & 3) << 7;
  int bb = bw >> 6, hi = (bw >> 3) & 7, wi = bw & 7;

  {  // stage A: rows gathered by window partition, fp32 -> bf16 (native RNE casts)
    int row = tid >> 1;
    int n = n0 + row;
    int tt = n >> 6, ii = (n >> 3) & 7, jj = n & 7;
    const float* src = x + ((((long)(bb * 8 + tt)) * 64 + (hi * 8 + ii)) * 64 + (wi * 8 + jj)) * 256;
    int fb = (tid & 1) * 4;
#pragma unroll
    for (int u = 0; u < 32; ++u) {
      int f = fb + u * 8;
      float4 d = *(const float4*)(src + f);
      __bf16 h0 = (__bf16)d.x, h1 = (__bf16)d.y, h2 = (__bf16)d.z, h3 = (__bf16)d.w;
      __bf16* dst = (__bf16*)&As[row][f];
      dst[0] = h0; dst[1] = h1; dst[2] = h2; dst[3] = h3;
    }
  }
  __syncthreads();

  int wid = tid >> 6, lane = tid & 63;
  int lg = lane >> 4, lr = lane & 15;
  int wr = wid >> 1, wc = wid & 1;

  for (int nt = 0; nt < 6; ++nt) {
    f32x4 acc[4][4];
#pragma unroll
    for (int a = 0; a < 4; ++a)
#pragma unroll
      for (int b2 = 0; b2 < 4; ++b2) acc[a][b2] = (f32x4){0.f, 0.f, 0.f, 0.f};

    for (int kk = 0; kk < 256; kk += 32) {
      __syncthreads();
      {
        int brow = tid >> 1, bh2 = tid & 1;
        const uint4* bs = (const uint4*)(wqT + ((long)(nt * 128 + brow)) * 256 + kk + bh2 * 16);
        uint4 b0 = bs[0], b1 = bs[1];
        *(uint4*)&Bs[brow][bh2 * 16] = b0;
        *(uint4*)&Bs[brow][bh2 * 16 + 8] = b1;
      }
      __syncthreads();
      bf16x8 af[4], bfr[4];
#pragma unroll
      for (int mi = 0; mi < 4; ++mi)
        af[mi] = *(const bf16x8*)&As[wr * 64 + mi * 16 + lr][kk + lg * 8];
#pragma unroll
      for (int ni = 0; ni < 4; ++ni)
        bfr[ni] = *(const bf16x8*)&Bs[wc * 64 + ni * 16 + lr][lg * 8];
#pragma unroll
      for (int mi = 0; mi < 4; ++mi)
#pragma unroll
        for (int ni = 0; ni < 4; ++ni)
          acc[mi][ni] = __builtin_amdgcn_mfma_f32_16x16x32_bf16(af[mi], bfr[ni], acc[mi][ni], 0, 0, 0);
    }
    // epilogue: split q/k/v by output column; layout [bw*8+head][n][32] bf16
#pragma unroll
    for (int ni = 0; ni < 4; ++ni) {
      int c = nt * 128 + wc * 64 + ni * 16 + lr;
      int which = c >> 8, head = (c >> 5) & 7, d = c & 31;
      unsigned short* dst = (which == 0) ? qo : ((which == 1) ? ko : vo);
      long base = ((long)(bw * 8 + head)) * NTOK * DH + d;
#pragma unroll
      for (int mi = 0; mi < 4; ++mi) {
        int nloc = n0 + wr * 64 + mi * 16 + lg * 4;
#pragma unroll
        for (int r = 0; r < 4; ++r) {
          __bf16 hv = (__bf16)acc[mi][ni][r];
          dst[base + (long)(nloc + r) * DH] = __builtin_bit_cast(unsigned short, hv);
        }
      }
    }
  }
}

// ---------------- kernel 2: attention per (window, head) ----------------
// grid 1024 blocks, 256 thr (4 waves). ROUND-3-VERIFIED LDS layouts:
//   K   [512 n][80B]  @0      (40960B)  (32 bf16 + 8 pad)
//   V^T [32 d][1040B] @40960  (33280B)  (512 bf16 + 8 pad)
//   P   per wave [16][80B] @74240 (4*1280B)  -- single buffer, frag0/frag1 sequential
// Total 79360B -> 2 blocks/CU. Each wave: 32 q-rows/pass (2 frags), 4 passes:
// kf/vf LDS reads each feed 2 MFMAs (halved vs round 3).
#define VTOFF 40960
#define POFF 74240
__global__ __launch_bounds__(256, 2) void k_attn(
    const unsigned short* __restrict__ qg0, const unsigned short* __restrict__ kg0,
    const unsigned short* __restrict__ vg0, unsigned short* __restrict__ og) {
  extern __shared__ char smem[];
  int bh = blockIdx.x;
  int tid = threadIdx.x;
  const unsigned short* qg = qg0 + (long)bh * NTOK * DH;
  const unsigned short* kg = kg0 + (long)bh * NTOK * DH;
  const unsigned short* vg = vg0 + (long)bh * NTOK * DH;

  // stage K: [n][d] rows of 32 bf16, padded to 40 (round-3 verified)
#pragma unroll
  for (int i2 = 0; i2 < 8; ++i2) {
    int ci = tid + i2 * 256;  // 16B chunk id: n = ci>>2, quarter h = ci&3
    uint4 dd = *(const uint4*)(kg + ci * 8);
    int n = ci >> 2, h = ci & 3;
    *(uint4*)(smem + n * 80 + h * 16) = dd;
  }
  // stage V^T: thread t owns rows n=2t,2t+1; column u32 writes (round-3 verified)
  {
    const uint4* vs = (const uint4*)(vg + tid * 64);
    unsigned r0[16], r1[16];
    *(uint4*)&r0[0] = vs[0]; *(uint4*)&r0[4] = vs[1]; *(uint4*)&r0[8] = vs[2]; *(uint4*)&r0[12] = vs[3];
    *(uint4*)&r1[0] = vs[4]; *(uint4*)&r1[4] = vs[5]; *(uint4*)&r1[8] = vs[6]; *(uint4*)&r1[12] = vs[7];
#pragma unroll
    for (int d = 0; d < 32; ++d) {
      unsigned lo  = (r0[d >> 1] >> ((d & 1) * 16)) & 0xffffu;
      unsigned hi2 = (r1[d >> 1] >> ((d & 1) * 16)) & 0xffffu;
      *(unsigned*)(smem + VTOFF + d * 1040 + tid * 4) = lo | (hi2 << 16);
    }
  }
  __syncthreads();

  int wid = tid >> 6, lane = tid & 63;
  int lg = lane >> 4, lr = lane & 15;
  char* Pb = smem + POFF + wid * 1280;
  unsigned short* ob = og + (long)bh * NTOK * DH;  // block-contiguous O [n][32]
  const f32x4 zf = {0.f, 0.f, 0.f, 0.f};

  for (int pass = 0; pass < 4; ++pass) {
    int qA = pass * 128 + wid * 32;
    bf16x8 qf0 = *(const bf16x8*)(qg + (qA + lr) * DH + lg * 8);
    bf16x8 qf1 = *(const bf16x8*)(qg + (qA + 16 + lr) * DH + lg * 8);
    f32x4 o00 = zf, o01 = zf, o10 = zf, o11 = zf;
    float m0 = -1e30f, m1 = -1e30f, sum0 = 0.f, sum1 = 0.f;

    for (int ch = 0; ch < 4; ++ch) {
      f32x4 s0[8], s1[8];
#pragma unroll
      for (int t = 0; t < 8; ++t) {
        bf16x8 kf = *(const bf16x8*)(smem + ((ch * 8 + t) * 16 + lr) * 80 + lg * 16);
        s0[t] = __builtin_amdgcn_mfma_f32_16x16x32_bf16(kf, qf0, zf, 0, 0, 0);
        s1[t] = __builtin_amdgcn_mfma_f32_16x16x32_bf16(kf, qf1, zf, 0, 0, 0);
      }
      // chunk max per q-row (q = lr), reduce across lg groups via xor 16/32
      float mc0 = -1e30f, mc1 = -1e30f;
#pragma unroll
      for (int t = 0; t < 8; ++t)
#pragma unroll
        for (int r = 0; r < 4; ++r) {
          mc0 = fmaxf(mc0, s0[t][r]);
          mc1 = fmaxf(mc1, s1[t][r]);
        }
      mc0 = fmaxf(mc0, __shfl_xor(mc0, 16, 64));
      mc0 = fmaxf(mc0, __shfl_xor(mc0, 32, 64));
      mc1 = fmaxf(mc1, __shfl_xor(mc1, 16, 64));
      mc1 = fmaxf(mc1, __shfl_xor(mc1, 32, 64));
      float nm0 = fmaxf(m0, mc0), nm1 = fmaxf(m1, mc1);
      float sc0 = __builtin_amdgcn_exp2f(m0 - nm0);
      float sc1 = __builtin_amdgcn_exp2f(m1 - nm1);
      m0 = nm0; m1 = nm1;
      float ps0 = 0.f, ps1 = 0.f;
#pragma unroll
      for (int t = 0; t < 8; ++t)
#pragma unroll
        for (int r = 0; r < 4; ++r) {
          float p0 = __builtin_amdgcn_exp2f(s0[t][r] - nm0);
          float p1 = __builtin_amdgcn_exp2f(s1[t][r] - nm1);
          s0[t][r] = p0; s1[t][r] = p1;
          ps0 += p0; ps1 += p1;
        }
      ps0 += __shfl_xor(ps0, 16, 64);
      ps0 += __shfl_xor(ps0, 32, 64);
      ps1 += __shfl_xor(ps1, 16, 64);
      ps1 += __shfl_xor(ps1, 32, 64);
      sum0 = sum0 * sc0 + ps0;
      sum1 = sum1 * sc1 + ps1;
      // rescale O accumulators (lane (lg,lr) holds O[q-local=4lg+r][d=lr])
#pragma unroll
      for (int r = 0; r < 4; ++r) {
        float so0 = __shfl(sc0, lg * 4 + r, 64);
        float so1 = __shfl(sc1, lg * 4 + r, 64);
        o00[r] *= so0; o01[r] *= so0;
        o10[r] *= so1; o11[r] *= so1;
      }
      // PV: 4 groups of 32 m-cols; P bounced via per-wave LDS [16][80B].
      // Shared vf reads feed both frags; P buffer reused frag0 then frag1
      // (DS ops are in-order within a wave).
#pragma unroll
      for (int mcl = 0; mcl < 4; ++mcl) {
        int mg = ch * 4 + mcl;
        bf16x8 vf0 = *(const bf16x8*)(smem + VTOFF + (lr) * 1040 + mg * 64 + lg * 16);
        bf16x8 vf1 = *(const bf16x8*)(smem + VTOFF + (16 + lr) * 1040 + mg * 64 + lg * 16);
        // frag0
#pragma unroll
        for (int u = 0; u < 2; ++u) {
          int t = mcl * 2 + u;
          __bf16* pw = (__bf16*)(Pb + lr * 80 + u * 32 + lg * 8);
          pw[0] = (__bf16)s0[t][0]; pw[1] = (__bf16)s0[t][1];
          pw[2] = (__bf16)s0[t][2]; pw[3] = (__bf16)s0[t][3];
        }
        bf16x8 pf0 = *(const bf16x8*)(Pb + lr * 80 + lg * 16);
        o00 = __builtin_amdgcn_mfma_f32_16x16x32_bf16(pf0, vf0, o00, 0, 0, 0);
        o01 = __builtin_amdgcn_mfma_f32_16x16x32_bf16(pf0, vf1, o01, 0, 0, 0);
        // frag1 (reuse buffer)
#pragma unroll
        for (int u = 0; u < 2; ++u) {
          int t = mcl * 2 + u;
          __bf16* pw = (__bf16*)(Pb + lr * 80 + u * 32 + lg * 8);
          pw[0] = (__bf16)s1[t][0]; pw[1] = (__bf16)s1[t][1];
          pw[2] = (__bf16)s1[t][2]; pw[3] = (__bf16)s1[t][3];
        }
        bf16x8 pf1 = *(const bf16x8*)(Pb + lr * 80 + lg * 16);
        o10 = __builtin_amdgcn_mfma_f32_16x16x32_bf16(pf1, vf0, o10, 0, 0, 0);
        o11 = __builtin_amdgcn_mfma_f32_16x16x32_bf16(pf1, vf1, o11, 0, 0, 0);
      }
    }

    // normalize + transpose through Pb -> contiguous 16B stores (frag0 then frag1)
    float rcp0 = 1.0f / sum0, rcp1 = 1.0f / sum1;
#pragma unroll
    for (int r = 0; r < 4; ++r) {
      float rr0 = __shfl(rcp0, lg * 4 + r, 64);
      int rowb = (lg * 4 + r) * 80;
      *(__bf16*)(Pb + rowb + lr * 2)      = (__bf16)(o00[r] * rr0);
      *(__bf16*)(Pb + rowb + 32 + lr * 2) = (__bf16)(o01[r] * rr0);
    }
    {
      int row = lane >> 2, qq = lane & 3;
      uint4 d0 = *(const uint4*)(Pb + row * 80 + qq * 16);
      *(uint4*)(ob + ((long)(qA + row)) * DH + qq * 8) = d0;
    }
#pragma unroll
    for (int r = 0; r < 4; ++r) {
      float rr1 = __shfl(rcp1, lg * 4 + r, 64);
      int rowb = (lg * 4 + r) * 80;
      *(__bf16*)(Pb + rowb + lr * 2)      = (__bf16)(o10[r] * rr1);
      *(__bf16*)(Pb + rowb + 32 + lr * 2) = (__bf16)(o11[r] * rr1);
    }
    {
      int row = lane >> 2, qq = lane & 3;
      uint4 d1 = *(const uint4*)(Pb + row * 80 + qq * 16);
      *(uint4*)(ob + ((long)(qA + 16 + row)) * DH + qq * 8) = d1;
    }
  }
}

// ---------------- kernel 3: proj GEMM + bias + window reverse ----------------
__global__ __launch_bounds__(256, 2) void k_proj(
    const unsigned short* __restrict__ og, const unsigned short* __restrict__ wpT,
    const float* __restrict__ pb, float* __restrict__ out) {
  extern __shared__ char smem[];
  unsigned short (*As)[264] = (unsigned short (*)[264])smem;
  unsigned short (*Bs)[40]  = (unsigned short (*)[40])(smem + 128 * 264 * 2);
  int tid = threadIdx.x;
  int mtile = blockIdx.x;
  int bw = mtile >> 2;
  int n0 = (mtile & 3) << 7;
  int bb = bw >> 6, hi = (bw >> 3) & 7, wi = bw & 7;

  {  // stage A from O layout [bw*8+head][n][32]: 64B (4 x uint4) per head per row
    int row = tid >> 1, hf = tid & 1;
#pragma unroll
    for (int h4 = 0; h4 < 4; ++h4) {
      int h = hf * 4 + h4;
      const uint4* asrc = (const uint4*)(og + (((long)(bw * 8 + h)) * NTOK + n0 + row) * DH);
      uint4 d0 = asrc[0], d1 = asrc[1], d2 = asrc[2], d3 = asrc[3];
      *(uint4*)&As[row][h * 32]      = d0;
      *(uint4*)&As[row][h * 32 + 8]  = d1;
      *(uint4*)&As[row][h * 32 + 16] = d2;
      *(uint4*)&As[row][h * 32 + 24] = d3;
    }
  }
  __syncthreads();

  int wid = tid >> 6, lane = tid & 63;
  int lg = lane >> 4, lr = lane & 15;
  int wr = wid >> 1, wc = wid & 1;

  for (int nt = 0; nt < 2; ++nt) {
    f32x4 acc[4][4];
#pragma unroll
    for (int a = 0; a < 4; ++a)
#pragma unroll
      for (int b2 = 0; b2 < 4; ++b2) acc[a][b2] = (f32x4){0.f, 0.f, 0.f, 0.f};

    for (int kk = 0; kk < 256; kk += 32) {
      __syncthreads();
      {
        int brow = tid >> 1, bh2 = tid & 1;
        const uint4* bs = (const uint4*)(wpT + ((long)(nt * 128 + brow)) * 256 + kk + bh2 * 16);
        uint4 b0 = bs[0], b1 = bs[1];
        *(uint4*)&Bs[brow][bh2 * 16] = b0;
        *(uint4*)&Bs[brow][bh2 * 16 + 8] = b1;
      }
      __syncthreads();
      bf16x8 af[4], bfr[4];
#pragma unroll
      for (int mi = 0; mi < 4; ++mi)
        af[mi] = *(const bf16x8*)&As[wr * 64 + mi * 16 + lr][kk + lg * 8];
#pragma unroll
      for (int ni = 0; ni < 4; ++ni)
        bfr[ni] = *(const bf16x8*)&Bs[wc * 64 + ni * 16 + lr][lg * 8];
#pragma unroll
      for (int mi = 0; mi < 4; ++mi)
#pragma unroll
        for (int ni = 0; ni < 4; ++ni)
          acc[mi][ni] = __builtin_amdgcn_mfma_f32_16x16x32_bf16(af[mi], bfr[ni], acc[mi][ni], 0, 0, 0);
    }
    // epilogue: bias + window reverse, coalesced fp32 (16 lanes -> 64B)
#pragma unroll
    for (int ni = 0; ni < 4; ++ni) {
      int c = nt * 128 + wc * 64 + ni * 16 + lr;
      float bias = pb[c];
#pragma unroll
      for (int mi = 0; mi < 4; ++mi) {
        int nbase = n0 + wr * 64 + mi * 16 + lg * 4;
#pragma unroll
        for (int r = 0; r < 4; ++r) {
          int n = nbase + r;
          int tt = n >> 6, ii = (n >> 3) & 7, jj = n & 7;
          long off = ((((long)(bb * 8 + tt)) * 64 + (hi * 8 + ii)) * 64 + (wi * 8 + jj)) * 256 + c;
          out[off] = acc[mi][ni][r] + bias;
        }
      }
    }
  }
}

extern "C" void kernel_launch(void* const* d_in, const int* in_sizes, int n_in,
                              void* d_out, int out_size, void* d_ws, size_t ws_size,
                              hipStream_t stream) {
  const float* x      = (const float*)d_in[0];
  const float* qkv_w  = (const float*)d_in[1];
  const float* proj_w = (const float*)d_in[2];
  const float* proj_b = (const float*)d_in[3];
  float* out = (float*)d_out;
  char* ws = (char*)d_ws;

  // workspace layout (bytes): wqT 393216 | wpT 131072 | Q 32MiB | K 32MiB | V 32MiB | O 32MiB
  unsigned short* wqT = (unsigned short*)(ws);
  unsigned short* wpT = (unsigned short*)(ws + 393216);
  unsigned short* Q   = (unsigned short*)(ws + 524288);
  unsigned short* K   = (unsigned short*)(ws + 524288 + 1L * 33554432);
  unsigned short* V   = (unsigned short*)(ws + 524288 + 2L * 33554432);
  unsigned short* O   = (unsigned short*)(ws + 524288 + 3L * 33554432);

  (void)hipFuncSetAttribute((const void*)k_qkv,  hipFuncAttributeMaxDynamicSharedMemorySize, 77824);
  (void)hipFuncSetAttribute((const void*)k_attn, hipFuncAttributeMaxDynamicSharedMemorySize, 79360);
  (void)hipFuncSetAttribute((const void*)k_proj, hipFuncAttributeMaxDynamicSharedMemorySize, 77824);

  k_prep<<<256, 256, 0, stream>>>(qkv_w, proj_w, wqT, wpT);
  k_qkv<<<512, 256, 77824, stream>>>(x, wqT, Q, K, V);
  k_attn<<<1024, 256, 79360, stream>>>(Q, K, V, O);
  k_proj<<<512, 256, 77824, stream>>>(O, wpT, proj_b, out);
}